// Round 4
// baseline (150.794 us; speedup 1.0000x reference)
//
#include <hip/hip_runtime.h>
#include <math.h>

#define HID 1536
#define NEXP 8
#define NF4 (HID / 4)          // 384 float4 per token row
#define TOKS_PER_BLOCK 32      // 4 waves * 8 tokens/wave

// Layout: q = lane&15 is the H-slice (24 float4 each), tg = lane>>4 the token
// group. Each lane accumulates 8 expert dots for TWO tokens (tA = base+tg,
// tB = base+tg+4) over its slice, so every weight float4 read from LDS feeds
// 8 FMAs instead of 4 (halves LDS-pipe traffic vs 1 token/lane).
// Butterfly over the 16-lane slice group then yields full logits everywhere.
__global__ __launch_bounds__(256) void router_topk_kernel(
    const float* __restrict__ hs,
    const float* __restrict__ wgt,
    const float* __restrict__ bias,
    float* __restrict__ out,
    int T)
{
    __shared__ float4 wlds[NEXP * NF4];   // 48 KB: full weight matrix

    const int tid = threadIdx.x;

    // Stage weights global -> LDS, coalesced float4 copy (12 per thread).
    const float4* wg4 = reinterpret_cast<const float4*>(wgt);
    #pragma unroll
    for (int i = 0; i < (NEXP * NF4) / 256; ++i)
        wlds[tid + i * 256] = wg4[tid + i * 256];
    __syncthreads();

    const int lane = tid & 63;
    const int wid  = tid >> 6;
    const int q    = lane & 15;    // 16 slices of 24 float4
    const int tg   = lane >> 4;    // 4 token groups
    const int base = blockIdx.x * TOKS_PER_BLOCK + wid * 8;
    const int tA   = base + tg;
    const int tB   = base + tg + 4;

    const float4* rowA = reinterpret_cast<const float4*>(hs) + (size_t)tA * NF4;
    const float4* rowB = reinterpret_cast<const float4*>(hs) + (size_t)tB * NF4;

    float accA[NEXP], accB[NEXP];
    #pragma unroll
    for (int e = 0; e < NEXP; ++e) { accA[e] = 0.0f; accB[e] = 0.0f; }

    // 24 k-steps per lane, chunked by 6: 12 global loads in flight per chunk.
    #pragma unroll
    for (int c = 0; c < 4; ++c) {
        float4 hA[6], hB[6];
        #pragma unroll
        for (int j = 0; j < 6; ++j) {
            hA[j] = rowA[(c * 6 + j) * 16 + q];
            hB[j] = rowB[(c * 6 + j) * 16 + q];
        }
        #pragma unroll
        for (int j = 0; j < 6; ++j) {
            #pragma unroll
            for (int e = 0; e < NEXP; ++e) {
                const float4 wv = wlds[e * NF4 + (c * 6 + j) * 16 + q];
                accA[e] = fmaf(hA[j].x, wv.x, accA[e]);
                accA[e] = fmaf(hA[j].y, wv.y, accA[e]);
                accA[e] = fmaf(hA[j].z, wv.z, accA[e]);
                accA[e] = fmaf(hA[j].w, wv.w, accA[e]);
                accB[e] = fmaf(hB[j].x, wv.x, accB[e]);
                accB[e] = fmaf(hB[j].y, wv.y, accB[e]);
                accB[e] = fmaf(hB[j].z, wv.z, accB[e]);
                accB[e] = fmaf(hB[j].w, wv.w, accB[e]);
            }
        }
    }

    // Reduce across the 16-lane slice group (masks 1,2,4,8): every lane ends
    // with both tokens' full logits.
    #pragma unroll
    for (int m = 1; m <= 8; m <<= 1) {
        #pragma unroll
        for (int e = 0; e < NEXP; ++e) {
            accA[e] += __shfl_xor(accA[e], m, 64);
            accB[e] += __shfl_xor(accB[e], m, 64);
        }
    }

    // scores = sigmoid(logits); choice scores add the correction bias.
    float sA[NEXP], scA[NEXP], sB[NEXP], scB[NEXP];
    #pragma unroll
    for (int e = 0; e < NEXP; ++e) {
        const float be = bias[e];
        sA[e]  = 1.0f / (1.0f + expf(-accA[e]));
        scA[e] = sA[e] + be;
        sB[e]  = 1.0f / (1.0f + expf(-accB[e]));
        scB[e] = sB[e] + be;
    }

    // top-2 on sc, lowest-index-first tie-break (matches jax.lax.top_k).
    // Scalar-tracked weights avoid runtime-indexed register arrays.
    int   a0 = 0;
    float av0 = scA[0], aw0 = sA[0];
    #pragma unroll
    for (int e = 1; e < NEXP; ++e)
        if (scA[e] > av0) { av0 = scA[e]; aw0 = sA[e]; a0 = e; }
    int   a1 = -1;
    float av1 = -3.4e38f, aw1 = 0.0f;
    #pragma unroll
    for (int e = 0; e < NEXP; ++e)
        if (e != a0 && scA[e] > av1) { av1 = scA[e]; aw1 = sA[e]; a1 = e; }
    const float ainv = 1.0f / (aw0 + aw1 + 1e-20f);

    int   b0 = 0;
    float bv0 = scB[0], bw0 = sB[0];
    #pragma unroll
    for (int e = 1; e < NEXP; ++e)
        if (scB[e] > bv0) { bv0 = scB[e]; bw0 = sB[e]; b0 = e; }
    int   b1 = -1;
    float bv1 = -3.4e38f, bw1 = 0.0f;
    #pragma unroll
    for (int e = 0; e < NEXP; ++e)
        if (e != b0 && scB[e] > bv1) { bv1 = scB[e]; bw1 = sB[e]; b1 = e; }
    const float binv = 1.0f / (bw0 + bw1 + 1e-20f);

    // lanes q==0/1 write token A's pos 0/1; q==2/3 write token B's pos 0/1.
    if (q < 2 && tA < T) {
        out[tA * 2 + q]         = (q == 0) ? (float)a0 : (float)a1;
        out[T * 2 + tA * 2 + q] = ((q == 0) ? aw0 : aw1) * ainv;
    }
    if (q >= 2 && q < 4 && tB < T) {
        const int p = q - 2;
        out[tB * 2 + p]         = (p == 0) ? (float)b0 : (float)b1;
        out[T * 2 + tB * 2 + p] = ((p == 0) ? bw0 : bw1) * binv;
    }
}

extern "C" void kernel_launch(void* const* d_in, const int* in_sizes, int n_in,
                              void* d_out, int out_size, void* d_ws, size_t ws_size,
                              hipStream_t stream)
{
    const float* hs   = (const float*)d_in[0];   // (4,4096,1536) f32
    const float* wgt  = (const float*)d_in[1];   // (8,1536) f32
    const float* bias = (const float*)d_in[2];   // (8,) f32
    float* out = (float*)d_out;                  // [2T idx | 2T weights] f32

    const int T = in_sizes[0] / HID;             // 16384
    const int blocks = (T + TOKS_PER_BLOCK - 1) / TOKS_PER_BLOCK;
    router_topk_kernel<<<blocks, 256, 0, stream>>>(hs, wgt, bias, out, T);
}